// Round 1
// baseline (492.110 us; speedup 1.0000x reference)
//
#include <hip/hip_runtime.h>

#define SCALE_F 0.08838834764831845f
#define NEG_INF -1e30f

constexpr int S    = 32;
constexpr int Hq   = 32;
constexpr int Hkv  = 8;
constexpr int G    = 4;     // Hq / Hkv
constexpr int D    = 128;
constexpr int BS   = 16;    // kv positions per cache block
constexpr int BMAX = 128;   // max cache blocks per seq
constexpr int KMAX = BMAX * BS;  // 2048

// ---------------------------------------------------------------------------
// Kernel 1: per (s, kv-head, part) partial attention.
// 256 threads. Pass 1: scores -> LDS. Softmax (unnormalized p, track m,l).
// Pass 2: p @ V -> partial acc. Partials to workspace.
// ---------------------------------------------------------------------------
__global__ __launch_bounds__(256, 4)
void attn_part_kernel(const float* __restrict__ q_ptr,
                      const float* __restrict__ kc,
                      const float* __restrict__ vc,
                      const int*   __restrict__ bt,
                      const int*   __restrict__ slens,
                      const float* __restrict__ slopes,
                      float* __restrict__ part_acc,
                      float* __restrict__ part_m,
                      float* __restrict__ part_l,
                      int parts, int chunk)
{
    extern __shared__ float smem[];
    float* sm_s   = smem;              // G * chunk  (scores, then p)
    float* sm_acc = smem + G * chunk;  // G * D      (half-combine)

    const int bid  = blockIdx.x;
    const int part = bid % parts;
    const int sh   = bid / parts;      // s*Hkv + h
    const int h    = sh % Hkv;
    const int s    = sh / Hkv;

    const int seq_len   = slens[s];
    const int num_parts = (seq_len + chunk - 1) / chunk;
    if (part >= num_parts) return;

    const int tid      = threadIdx.x;
    const int cpb      = chunk / BS;                 // kv blocks per part
    const int kvb0     = part * cpb;                 // first kv block
    const int nb_total = (seq_len + BS - 1) / BS;    // valid kv blocks for seq

    float slope[G];
    #pragma unroll
    for (int g = 0; g < G; ++g) slope[g] = slopes[h * G + g];
    const float ctx = (float)(seq_len - 1);

    // ---------------- Pass 1: scores ----------------
    const int o = tid >> 4;   // position within kv block (0..15)
    const int t = tid & 15;   // d-chunk index (0..15), covers d = t*8 .. t*8+7

    float4 qa[G], qb[G];
    #pragma unroll
    for (int g = 0; g < G; ++g) {
        const float* qp = q_ptr + ((size_t)(s * Hq + h * G + g) * D + t * 8);
        qa[g] = ((const float4*)qp)[0];
        qb[g] = ((const float4*)qp)[1];
    }

    for (int i = 0; i < cpb; ++i) {
        const int kvb = kvb0 + i;
        float sc[G];
        if (kvb < nb_total) {
            const int phys = bt[s * BMAX + kvb];
            const float* kp = kc + ((((size_t)phys * Hkv + h) * (D / 8) + t) * BS + o) * 8;
            float4 ka = ((const float4*)kp)[0];
            float4 kb = ((const float4*)kp)[1];
            #pragma unroll
            for (int g = 0; g < G; ++g) {
                sc[g] = qa[g].x * ka.x + qa[g].y * ka.y + qa[g].z * ka.z + qa[g].w * ka.w
                      + qb[g].x * kb.x + qb[g].y * kb.y + qb[g].z * kb.z + qb[g].w * kb.w;
            }
            #pragma unroll
            for (int g = 0; g < G; ++g) {
                #pragma unroll
                for (int msk = 8; msk >= 1; msk >>= 1)
                    sc[g] += __shfl_xor(sc[g], msk, 16);
            }
            const int kpos = kvb * BS + o;
            const bool valid = kpos < seq_len;
            #pragma unroll
            for (int g = 0; g < G; ++g)
                sc[g] = valid ? (SCALE_F * sc[g] + slope[g] * ((float)kpos - ctx)) : NEG_INF;
        } else {
            #pragma unroll
            for (int g = 0; g < G; ++g) sc[g] = NEG_INF;
        }
        if (t == 0) {
            #pragma unroll
            for (int g = 0; g < G; ++g) sm_s[g * chunk + i * BS + o] = sc[g];
        }
    }
    __syncthreads();

    // ---------------- softmax: wave w handles g = w ----------------
    {
        const int g    = tid >> 6;   // 4 waves, 4 groups
        const int lane = tid & 63;
        float m = NEG_INF;
        for (int j = lane; j < chunk; j += 64) m = fmaxf(m, sm_s[g * chunk + j]);
        #pragma unroll
        for (int msk = 32; msk >= 1; msk >>= 1) m = fmaxf(m, __shfl_xor(m, msk, 64));
        float l = 0.f;
        for (int j = lane; j < chunk; j += 64) {
            float p = __expf(sm_s[g * chunk + j] - m);
            sm_s[g * chunk + j] = p;
            l += p;
        }
        #pragma unroll
        for (int msk = 32; msk >= 1; msk >>= 1) l += __shfl_xor(l, msk, 64);
        if (lane == 0) {
            part_m[(sh * parts + part) * G + g] = m;
            part_l[(sh * parts + part) * G + g] = l;
        }
    }
    __syncthreads();

    // ---------------- Pass 2: p @ V ----------------
    const int d    = tid & 127;
    const int half = tid >> 7;
    float acc[G] = {0.f, 0.f, 0.f, 0.f};
    const int cpb_valid = min(cpb, nb_total - kvb0);
    for (int i = half; i < cpb_valid; i += 2) {
        const int phys = bt[s * BMAX + kvb0 + i];
        const float* vp = vc + (((size_t)phys * Hkv + h) * D + d) * BS;
        float4 v0 = ((const float4*)vp)[0];
        float4 v1 = ((const float4*)vp)[1];
        float4 v2 = ((const float4*)vp)[2];
        float4 v3 = ((const float4*)vp)[3];
        #pragma unroll
        for (int g = 0; g < G; ++g) {
            const float4* pp = (const float4*)(sm_s + g * chunk + i * BS);
            float4 p0 = pp[0], p1 = pp[1], p2 = pp[2], p3 = pp[3];
            acc[g] += p0.x * v0.x + p0.y * v0.y + p0.z * v0.z + p0.w * v0.w;
            acc[g] += p1.x * v1.x + p1.y * v1.y + p1.z * v1.z + p1.w * v1.w;
            acc[g] += p2.x * v2.x + p2.y * v2.y + p2.z * v2.z + p2.w * v2.w;
            acc[g] += p3.x * v3.x + p3.y * v3.y + p3.z * v3.z + p3.w * v3.w;
        }
    }
    if (half == 1) {
        #pragma unroll
        for (int g = 0; g < G; ++g) sm_acc[g * D + d] = acc[g];
    }
    __syncthreads();
    if (half == 0) {
        float* outp = part_acc + (size_t)(sh * parts + part) * G * D;
        #pragma unroll
        for (int g = 0; g < G; ++g)
            outp[g * D + d] = acc[g] + sm_acc[g * D + d];
    }
}

// ---------------------------------------------------------------------------
// Kernel 2: combine partials across parts, normalize, write output.
// grid = S*Hkv blocks, 512 threads: (g = tid>>7, d = tid&127).
// ---------------------------------------------------------------------------
__global__ __launch_bounds__(512)
void attn_reduce_kernel(const float* __restrict__ part_acc,
                        const float* __restrict__ part_m,
                        const float* __restrict__ part_l,
                        const int*   __restrict__ slens,
                        float* __restrict__ out,
                        int parts, int chunk)
{
    const int sh  = blockIdx.x;      // s*Hkv + h
    const int s   = sh / Hkv;
    const int tid = threadIdx.x;
    const int g   = tid >> 7;
    const int d   = tid & 127;

    const int seq_len = slens[s];
    const int np = min(parts, (seq_len + chunk - 1) / chunk);

    float M = NEG_INF;
    for (int p = 0; p < np; ++p)
        M = fmaxf(M, part_m[(sh * parts + p) * G + g]);
    float L = 0.f, acc = 0.f;
    for (int p = 0; p < np; ++p) {
        const float w = __expf(part_m[(sh * parts + p) * G + g] - M);
        L += w * part_l[(sh * parts + p) * G + g];
        acc += w * part_acc[((size_t)(sh * parts + p) * G + g) * D + d];
    }
    out[(size_t)(sh * G + g) * D + d] = acc / (L + 1e-10f);
}

extern "C" void kernel_launch(void* const* d_in, const int* in_sizes, int n_in,
                              void* d_out, int out_size, void* d_ws, size_t ws_size,
                              hipStream_t stream)
{
    const float* q   = (const float*)d_in[0];
    const float* kc  = (const float*)d_in[1];
    const float* vc  = (const float*)d_in[2];
    const int*   bt  = (const int*)d_in[3];
    const int*   sl  = (const int*)d_in[4];
    const float* slp = (const float*)d_in[5];
    // d_in[6] (query_start_len) is arange(S+1) by construction: every row is a
    // decode row and the output scatter is identity -> not needed on device.

    int parts = 8;
    while (parts > 1 &&
           (size_t)S * Hkv * parts * G * (D + 2) * sizeof(float) > ws_size)
        parts >>= 1;
    const int chunk = KMAX / parts;

    float* part_acc = (float*)d_ws;
    float* part_m   = part_acc + (size_t)S * Hkv * parts * G * D;
    float* part_l   = part_m   + (size_t)S * Hkv * parts * G;

    const size_t lds = (size_t)(G * chunk + G * D) * sizeof(float);

    attn_part_kernel<<<S * Hkv * parts, 256, lds, stream>>>(
        q, kc, vc, bt, sl, slp, part_acc, part_m, part_l, parts, chunk);
    attn_reduce_kernel<<<S * Hkv, 512, 0, stream>>>(
        part_acc, part_m, part_l, sl, (float*)d_out, parts, chunk);
}

// Round 2
// 476.575 us; speedup vs baseline: 1.0326x; 1.0326x over previous
//
#include <hip/hip_runtime.h>

#define SCALE_F 0.08838834764831845f
#define NEG_INF -1e30f

constexpr int S    = 32;
constexpr int Hq   = 32;
constexpr int Hkv  = 8;
constexpr int G    = 4;     // Hq / Hkv
constexpr int D    = 128;
constexpr int BS   = 16;    // kv positions per cache block
constexpr int BMAX = 128;   // max cache blocks per seq
constexpr int KMAX = BMAX * BS;  // 2048

// ---------------------------------------------------------------------------
// Kernel 1: per (s, kv-head, part) partial attention, PARTS compile-time.
// 256 threads. Pass 1 (reg-double-buffered K): scores -> LDS. Softmax.
// Pass 2 (reg-double-buffered V): p @ V -> partial acc -> workspace.
// ---------------------------------------------------------------------------
template<int PARTS>
__global__ __launch_bounds__(256, 6)
void attn_part_kernel(const float* __restrict__ q_ptr,
                      const float* __restrict__ kc,
                      const float* __restrict__ vc,
                      const int*   __restrict__ bt,
                      const int*   __restrict__ slens,
                      const float* __restrict__ slopes,
                      float* __restrict__ part_acc,
                      float* __restrict__ part_m,
                      float* __restrict__ part_l)
{
    constexpr int CHUNK = KMAX / PARTS;   // kv positions per part
    constexpr int CPB   = CHUNK / BS;     // kv blocks per part

    __shared__ float sm_s[G * CHUNK];     // scores, then p
    __shared__ float sm_acc[G * D];       // half-combine buffer

    const int bid  = blockIdx.x;
    const int part = bid % PARTS;
    const int sh   = bid / PARTS;         // s*Hkv + h
    const int h    = sh % Hkv;
    const int s    = sh / Hkv;

    const int seq_len   = slens[s];
    const int num_parts = (seq_len + CHUNK - 1) / CHUNK;
    if (part >= num_parts) return;

    const int tid       = threadIdx.x;
    const int kvb0      = part * CPB;
    const int nb_total  = (seq_len + BS - 1) / BS;
    const int cpb_valid = min(CPB, nb_total - kvb0);  // >= 1 here
    const int lim       = cpb_valid * BS;             // positions with written scores

    float slope[G];
    #pragma unroll
    for (int g = 0; g < G; ++g) slope[g] = slopes[h * G + g];
    const float ctx = (float)(seq_len - 1);

    // Block-table entries for this part: uniform -> SGPRs, all issued up front.
    int phys[CPB];
    #pragma unroll
    for (int i = 0; i < CPB; ++i) phys[i] = bt[s * BMAX + kvb0 + i];

    // ---------------- Pass 1: scores ----------------
    const int o = tid >> 4;   // position within kv block (0..15)
    const int t = tid & 15;   // d-chunk index: d = t*8 .. t*8+7

    float4 qa[G], qb[G];
    #pragma unroll
    for (int g = 0; g < G; ++g) {
        const float* qp = q_ptr + ((size_t)(s * Hq + h * G + g) * D + t * 8);
        qa[g] = ((const float4*)qp)[0];
        qb[g] = ((const float4*)qp)[1];
    }

    float4 ka, kb, nka, nkb;
    {
        const float* kp = kc + ((((size_t)phys[0] * Hkv + h) * (D / 8) + t) * BS + o) * 8;
        ka = ((const float4*)kp)[0];
        kb = ((const float4*)kp)[1];
    }
    #pragma unroll
    for (int i = 0; i < CPB; ++i) {
        if (i >= cpb_valid) break;
        if (i + 1 < cpb_valid) {   // prefetch next K while computing current
            const float* kp = kc + ((((size_t)phys[i + 1] * Hkv + h) * (D / 8) + t) * BS + o) * 8;
            nka = ((const float4*)kp)[0];
            nkb = ((const float4*)kp)[1];
        }
        float sc[G];
        #pragma unroll
        for (int g = 0; g < G; ++g)
            sc[g] = qa[g].x * ka.x + qa[g].y * ka.y + qa[g].z * ka.z + qa[g].w * ka.w
                  + qb[g].x * kb.x + qb[g].y * kb.y + qb[g].z * kb.z + qb[g].w * kb.w;
        #pragma unroll
        for (int g = 0; g < G; ++g) {
            #pragma unroll
            for (int msk = 8; msk >= 1; msk >>= 1)
                sc[g] += __shfl_xor(sc[g], msk, 16);
        }
        const int kpos  = (kvb0 + i) * BS + o;
        const bool valid = kpos < seq_len;
        if (t == 0) {
            #pragma unroll
            for (int g = 0; g < G; ++g)
                sm_s[g * CHUNK + i * BS + o] =
                    valid ? (SCALE_F * sc[g] + slope[g] * ((float)kpos - ctx)) : NEG_INF;
        }
        ka = nka; kb = nkb;
    }
    __syncthreads();

    // ---------------- softmax: wave w handles g = w (bounded by lim) -------
    {
        const int g    = tid >> 6;
        const int lane = tid & 63;
        float m = NEG_INF;
        for (int j = lane; j < lim; j += 64) m = fmaxf(m, sm_s[g * CHUNK + j]);
        #pragma unroll
        for (int msk = 32; msk >= 1; msk >>= 1) m = fmaxf(m, __shfl_xor(m, msk, 64));
        float l = 0.f;
        for (int j = lane; j < lim; j += 64) {
            float p = __expf(sm_s[g * CHUNK + j] - m);
            sm_s[g * CHUNK + j] = p;
            l += p;
        }
        #pragma unroll
        for (int msk = 32; msk >= 1; msk >>= 1) l += __shfl_xor(l, msk, 64);
        if (lane == 0) {
            part_m[(sh * PARTS + part) * G + g] = m;
            part_l[(sh * PARTS + part) * G + g] = l;
        }
    }
    __syncthreads();

    // ---------------- Pass 2: p @ V (reg-double-buffered V) ----------------
    const int d    = tid & 127;
    const int half = tid >> 7;
    float acc[G] = {0.f, 0.f, 0.f, 0.f};

    float4 v0, v1, v2, v3, w0, w1, w2, w3;
    if (half < cpb_valid) {
        const float* vp = vc + (((size_t)phys[half] * Hkv + h) * D + d) * BS;
        v0 = ((const float4*)vp)[0]; v1 = ((const float4*)vp)[1];
        v2 = ((const float4*)vp)[2]; v3 = ((const float4*)vp)[3];
    }
    for (int i = half; i < cpb_valid; i += 2) {
        if (i + 2 < cpb_valid) {   // prefetch next V block row
            const float* vp = vc + (((size_t)phys[i + 2] * Hkv + h) * D + d) * BS;
            w0 = ((const float4*)vp)[0]; w1 = ((const float4*)vp)[1];
            w2 = ((const float4*)vp)[2]; w3 = ((const float4*)vp)[3];
        }
        #pragma unroll
        for (int g = 0; g < G; ++g) {
            const float4* pp = (const float4*)(sm_s + g * CHUNK + i * BS);
            float4 p0 = pp[0], p1 = pp[1], p2 = pp[2], p3 = pp[3];
            acc[g] += p0.x * v0.x + p0.y * v0.y + p0.z * v0.z + p0.w * v0.w;
            acc[g] += p1.x * v1.x + p1.y * v1.y + p1.z * v1.z + p1.w * v1.w;
            acc[g] += p2.x * v2.x + p2.y * v2.y + p2.z * v2.z + p2.w * v2.w;
            acc[g] += p3.x * v3.x + p3.y * v3.y + p3.z * v3.z + p3.w * v3.w;
        }
        v0 = w0; v1 = w1; v2 = w2; v3 = w3;
    }
    if (half == 1) {
        #pragma unroll
        for (int g = 0; g < G; ++g) sm_acc[g * D + d] = acc[g];
    }
    __syncthreads();
    if (half == 0) {
        float* outp = part_acc + (size_t)(sh * PARTS + part) * G * D;
        #pragma unroll
        for (int g = 0; g < G; ++g)
            outp[g * D + d] = acc[g] + sm_acc[g * D + d];
    }
}

// ---------------------------------------------------------------------------
// Kernel 2: combine partials across parts, normalize, write output.
// ---------------------------------------------------------------------------
__global__ __launch_bounds__(512)
void attn_reduce_kernel(const float* __restrict__ part_acc,
                        const float* __restrict__ part_m,
                        const float* __restrict__ part_l,
                        const int*   __restrict__ slens,
                        float* __restrict__ out,
                        int parts, int chunk)
{
    const int sh  = blockIdx.x;      // s*Hkv + h
    const int s   = sh / Hkv;
    const int tid = threadIdx.x;
    const int g   = tid >> 7;
    const int d   = tid & 127;

    const int seq_len = slens[s];
    const int np = min(parts, (seq_len + chunk - 1) / chunk);

    float M = NEG_INF;
    for (int p = 0; p < np; ++p)
        M = fmaxf(M, part_m[(sh * parts + p) * G + g]);
    float L = 0.f, acc = 0.f;
    for (int p = 0; p < np; ++p) {
        const float w = __expf(part_m[(sh * parts + p) * G + g] - M);
        L += w * part_l[(sh * parts + p) * G + g];
        acc += w * part_acc[((size_t)(sh * parts + p) * G + g) * D + d];
    }
    out[(size_t)(sh * G + g) * D + d] = acc / (L + 1e-10f);
}

extern "C" void kernel_launch(void* const* d_in, const int* in_sizes, int n_in,
                              void* d_out, int out_size, void* d_ws, size_t ws_size,
                              hipStream_t stream)
{
    const float* q   = (const float*)d_in[0];
    const float* kc  = (const float*)d_in[1];
    const float* vc  = (const float*)d_in[2];
    const int*   bt  = (const int*)d_in[3];
    const int*   sl  = (const int*)d_in[4];
    const float* slp = (const float*)d_in[5];
    // d_in[6] (query_start_len) is arange(S+1): all rows decode, identity scatter.

    auto ws_need = [](int p) {
        return (size_t)S * Hkv * p * G * (D + 2) * sizeof(float);
    };
    int parts = 16;
    while (parts > 1 && ws_need(parts) > ws_size) parts >>= 1;
    const int chunk = KMAX / parts;

    float* part_acc = (float*)d_ws;
    float* part_m   = part_acc + (size_t)S * Hkv * parts * G * D;
    float* part_l   = part_m   + (size_t)S * Hkv * parts * G;

    const dim3 grid1(S * Hkv * parts);
    switch (parts) {
    case 16: attn_part_kernel<16><<<grid1, 256, 0, stream>>>(q, kc, vc, bt, sl, slp, part_acc, part_m, part_l); break;
    case 8:  attn_part_kernel<8> <<<grid1, 256, 0, stream>>>(q, kc, vc, bt, sl, slp, part_acc, part_m, part_l); break;
    case 4:  attn_part_kernel<4> <<<grid1, 256, 0, stream>>>(q, kc, vc, bt, sl, slp, part_acc, part_m, part_l); break;
    case 2:  attn_part_kernel<2> <<<grid1, 256, 0, stream>>>(q, kc, vc, bt, sl, slp, part_acc, part_m, part_l); break;
    default: attn_part_kernel<1> <<<grid1, 256, 0, stream>>>(q, kc, vc, bt, sl, slp, part_acc, part_m, part_l); break;
    }
    attn_reduce_kernel<<<S * Hkv, 512, 0, stream>>>(
        part_acc, part_m, part_l, sl, (float*)d_out, parts, chunk);
}